// Round 20
// baseline (416.116 us; speedup 1.0000x reference)
//
#include <hip/hip_runtime.h>
#include <hip/hip_bf16.h>
#include <stdint.h>
#include <math.h>

typedef __bf16 bf16_t;
typedef __bf16 bf16x8 __attribute__((ext_vector_type(8)));
typedef __bf16 bf16x4 __attribute__((ext_vector_type(4)));
typedef float  f32x4  __attribute__((ext_vector_type(4)));
typedef long long i64_t;

typedef __attribute__((address_space(1))) const void global_cv;
typedef __attribute__((address_space(3))) void lds_v;

// Problem constants: B=16,H=64,W=80,C=256; GH=8,GW=10; heads=8,DH=32; INNER=1024
// qkvt layout (per window w, head h; elem offsets):
//   base = w*61440 + h*7680 ; Q[tok][32] at +0 ; K[tok][32] at +2560 ; V^T[32][80] at +5120

__device__ __forceinline__ int map_p_to_g(int p) {
    int w = p / 80, n = p - w * 80;
    int b  = w >> 6, h2 = (w >> 3) & 7, w2 = w & 7;
    int gh = n / 10, gw = n - gh * 10;
    return b * 5120 + (gh * 8 + h2) * 80 + (gw * 8 + w2);
}

// XOR swizzle for 128-B LDS rows: bits 4-6 ^= bits 7-9 (involution, keeps 16B align)
__device__ __forceinline__ int swz128(int b) { return b ^ (((b >> 7) & 7) << 4); }

// ---------------- weight convert+transpose: fp32 [K][N] -> bf16 [N][K] ----------------
__global__ __launch_bounds__(256) void wconv_k(const float* __restrict__ in,
                                               bf16_t* __restrict__ out, int N, int K)
{
    int i = blockIdx.x * 256 + threadIdx.x;
    int n = i / K, k = i - n * K;
    out[i] = (bf16_t)in[(size_t)k * N + n];
}

// ---------------- fc2 weight convert: fp32 [1024][256] -> fp8 e4m3 [256][1024], x16 ----------------
__global__ __launch_bounds__(256) void wconv8_k(const float* __restrict__ in,
                                                unsigned char* __restrict__ out)
{
    int c  = blockIdx.x * 256 + threadIdx.x;
    int n  = (c * 4) >> 10;
    int k0 = (c * 4) & 1023;
    float g0 = 16.f * in[(size_t)(k0 + 0) * 256 + n];
    float g1 = 16.f * in[(size_t)(k0 + 1) * 256 + n];
    float g2 = 16.f * in[(size_t)(k0 + 2) * 256 + n];
    float g3 = 16.f * in[(size_t)(k0 + 3) * 256 + n];
    int pk = __builtin_amdgcn_cvt_pk_fp8_f32(g0, g1, 0, false);
    pk     = __builtin_amdgcn_cvt_pk_fp8_f32(g2, g3, pk, true);
    *(int*)(out + (size_t)c * 4) = pk;
}

// ---------------- LayerNorm (one wave per row), optional partition permute ----------------
template <int PERM>
__global__ __launch_bounds__(256) void ln_k(const float* __restrict__ in,
                                            const float* __restrict__ gg,
                                            const float* __restrict__ bb,
                                            bf16_t* __restrict__ o)
{
    int row  = blockIdx.x * 4 + (threadIdx.x >> 6);
    int lane = threadIdx.x & 63;
    const float4 xv = *(const float4*)(in + (size_t)row * 256 + lane * 4);
    float s = xv.x + xv.y + xv.z + xv.w;
#pragma unroll
    for (int m = 1; m < 64; m <<= 1) s += __shfl_xor(s, m, 64);
    float mean = s * (1.f / 256.f);
    float d0 = xv.x - mean, d1 = xv.y - mean, d2 = xv.z - mean, d3 = xv.w - mean;
    float v = d0 * d0 + d1 * d1 + d2 * d2 + d3 * d3;
#pragma unroll
    for (int m = 1; m < 64; m <<= 1) v += __shfl_xor(v, m, 64);
    float rstd = rsqrtf(v * (1.f / 256.f) + 1e-5f);
    const float4 gv = *(const float4*)(gg + lane * 4);
    const float4 bv = *(const float4*)(bb + lane * 4);
    int orow = row;
    if (PERM) {
        int b = row / 5120, r1 = row - b * 5120;
        int h = r1 / 80, wv = r1 - h * 80;
        int gh = h >> 3, h2 = h & 7, gw = wv >> 3, w2 = wv & 7;
        orow = ((b * 8 + h2) * 8 + w2) * 80 + gh * 10 + gw;
    }
    bf16x4 ov;
    ov[0] = (bf16_t)(d0 * rstd * gv.x + bv.x);
    ov[1] = (bf16_t)(d1 * rstd * gv.y + bv.y);
    ov[2] = (bf16_t)(d2 * rstd * gv.z + bv.z);
    ov[3] = (bf16_t)(d3 * rstd * gv.w + bv.w);
    *(bf16x4*)(o + (size_t)orow * 256 + lane * 4) = ov;
}

// ---------------- 128x64-tile MFMA GEMM, high-residency + compile-time N/K ----------------
// Wave tile 32x64 (acc[2][4] = 32 AGPR; ~80 regs -> 6 waves/SIMD); block = 4 row-stacked
// waves, LDS 24KB. Compile-time NN/KK: K-loop fully unrolls, all addresses fold to
// base+immediate, scheduler can interleave next-step staging with current MFMAs.
// EPI 0: qkvt scatter; EPI 1: fp32 x[g]+ls*(acc+b) grid-reverse; EPI 2: fp8 16*gelu
template <int EPI, int NBX, int NN, int KK>
__device__ __forceinline__ void gemm_body(const bf16_t* __restrict__ A,
                                          const bf16_t* __restrict__ Bt,
                                          const float* __restrict__ bias,
                                          const float* __restrict__ xres,
                                          const float* __restrict__ ls,
                                          void* __restrict__ outp)
{
    __shared__ bf16_t At[128 * 64];   // 16 KB: 128 rows x 128 B
    __shared__ bf16_t Bl[64 * 64];    //  8 KB:  64 rows x 128 B
    const int t = threadIdx.x;
    const int wid = t >> 6, lane = t & 63;
    const int ln = lane & 15, kg = lane >> 4;

    const int f   = blockIdx.x;
    const int xcd = f & 7, jj = f >> 3;
    const int byx = (gridDim.x >> 3) / NBX;
    const int by  = xcd * byx + jj / NBX;
    const int bx  = jj % NBX;

    constexpr size_t Kb = (size_t)KK * 2;
    const char* Ab = (const char*)(A  + (size_t)by * 128 * KK);
    const char* Bb = (const char*)(Bt + (size_t)bx * 64 * KK);
    char* AtB = (char*)At;
    char* BlB = (char*)Bl;

    // hoisted staging maps (compile-time-friendly)
    int spa[4], sra[4], soa[4];
#pragma unroll
    for (int i = 0; i < 4; ++i) {
        spa[i] = (i * 256 + t) * 16;
        sra[i] = spa[i] >> 7;
        soa[i] = (spa[i] & 127) ^ ((sra[i] & 7) << 4);
    }
    int spb[2], srb[2], sob[2];
#pragma unroll
    for (int i = 0; i < 2; ++i) {
        spb[i] = (i * 256 + t) * 16;
        srb[i] = spb[i] >> 7;
        sob[i] = (spb[i] & 127) ^ ((srb[i] & 7) << 4);
    }

    const f32x4 fz = {0.f, 0.f, 0.f, 0.f};
    f32x4 acc[2][4];
#pragma unroll
    for (int i = 0; i < 2; ++i)
#pragma unroll
        for (int j = 0; j < 4; ++j) acc[i][j] = fz;

    constexpr int nsteps = KK >> 6;

#pragma unroll
    for (int s = 0; s < nsteps; ++s) {
        const size_t kb = (size_t)s * 128;
#pragma unroll
        for (int i = 0; i < 4; ++i)
            __builtin_amdgcn_global_load_lds((global_cv*)(Ab + (size_t)sra[i] * Kb + kb + soa[i]),
                                             (lds_v*)(AtB + spa[i]), 16, 0, 0);
#pragma unroll
        for (int i = 0; i < 2; ++i)
            __builtin_amdgcn_global_load_lds((global_cv*)(Bb + (size_t)srb[i] * Kb + kb + sob[i]),
                                             (lds_v*)(BlB + spb[i]), 16, 0, 0);
        __syncthreads();
#pragma unroll
        for (int kk = 0; kk < 2; ++kk) {
            bf16x8 av[2], bv[4];
#pragma unroll
            for (int mt = 0; mt < 2; ++mt) {
                int row = wid * 32 + mt * 16 + ln;
                av[mt] = *(const bf16x8*)(AtB + swz128(row * 128 + kk * 64 + kg * 16));
            }
#pragma unroll
            for (int nt = 0; nt < 4; ++nt) {
                int row = nt * 16 + ln;
                bv[nt] = *(const bf16x8*)(BlB + swz128(row * 128 + kk * 64 + kg * 16));
            }
            // swapped operands: D^T -> our row = ln, our cols = kg*4+r
#pragma unroll
            for (int mt = 0; mt < 2; ++mt)
#pragma unroll
                for (int nt = 0; nt < 4; ++nt)
                    acc[mt][nt] = __builtin_amdgcn_mfma_f32_16x16x32_bf16(bv[nt], av[mt], acc[mt][nt], 0, 0, 0);
        }
        __syncthreads();
    }

#pragma unroll
    for (int mt = 0; mt < 2; ++mt) {
        const int row = by * 128 + wid * 32 + mt * 16 + ln;
        const int wno = row / 80, tok = row - wno * 80;   // EPI 0
#pragma unroll
        for (int nt = 0; nt < 4; ++nt) {
            const int colb = bx * 64 + nt * 16 + kg * 4;
            const f32x4 a = acc[mt][nt];
            const float4 b4 = *(const float4*)(bias + colb);
            if constexpr (EPI == 0) {
                bf16_t* o = (bf16_t*)outp;
                const int typ = colb >> 8, h = (colb >> 5) & 7, d0 = colb & 31;
                const size_t base = (size_t)wno * 61440 + (size_t)h * 7680;
                if (typ < 2) {
                    bf16x4 ov;
                    ov[0] = (bf16_t)(a[0] + b4.x); ov[1] = (bf16_t)(a[1] + b4.y);
                    ov[2] = (bf16_t)(a[2] + b4.z); ov[3] = (bf16_t)(a[3] + b4.w);
                    *(bf16x4*)(o + base + typ * 2560 + tok * 32 + d0) = ov;
                } else {
#pragma unroll
                    for (int r = 0; r < 4; ++r)
                        o[base + 5120 + (size_t)(d0 + r) * 80 + tok] =
                            (bf16_t)(a[r] + ((const float*)&b4)[r]);
                }
            } else if constexpr (EPI == 1) {
                const float4 l4 = *(const float4*)(ls + colb);
                float* o = (float*)outp;
                int g = map_p_to_g(row);
                size_t idx = (size_t)g * 256 + colb;
                float4 xr = *(const float4*)(xres + idx);
                float4 r4;
                r4.x = xr.x + l4.x * (a[0] + b4.x);
                r4.y = xr.y + l4.y * (a[1] + b4.y);
                r4.z = xr.z + l4.z * (a[2] + b4.z);
                r4.w = xr.w + l4.w * (a[3] + b4.w);
                *(float4*)(o + idx) = r4;
            } else {   // fc1 -> fp8 h1 (x16)
                unsigned char* o = (unsigned char*)outp;
                float g4[4];
#pragma unroll
                for (int r = 0; r < 4; ++r) {
                    float u2 = a[r] + ((const float*)&b4)[r];
                    float e = __expf(-1.702f * u2);
                    g4[r] = (16.f * u2) * __builtin_amdgcn_rcpf(1.f + e);
                }
                int pk = __builtin_amdgcn_cvt_pk_fp8_f32(g4[0], g4[1], 0, false);
                pk     = __builtin_amdgcn_cvt_pk_fp8_f32(g4[2], g4[3], pk, true);
                *(int*)(o + (size_t)row * NN + colb) = pk;
            }
        }
    }
}

__global__ __launch_bounds__(256, 6) void gq_k(const bf16_t* A, const bf16_t* Bt, const float* bias,
                                               void* outp)
{ gemm_body<0, 12, 768, 256>(A, Bt, bias, nullptr, nullptr, outp); }

__global__ __launch_bounds__(256, 6) void gp_k(const bf16_t* A, const bf16_t* Bt, const float* bias,
                                               const float* xres, const float* ls, void* outp)
{ gemm_body<1, 4, 256, 256>(A, Bt, bias, xres, ls, outp); }

__global__ __launch_bounds__(256, 6) void g1_k(const bf16_t* A, const bf16_t* Bt, const float* bias,
                                               void* outp)
{ gemm_body<2, 16, 1024, 256>(A, Bt, bias, nullptr, nullptr, outp); }

// ---------------- fc2 GEMM in fp8 (r15, unchanged) ----------------
__global__ __launch_bounds__(256, 4) void g2f8_k(const unsigned char* __restrict__ A,
                                                 const unsigned char* __restrict__ Bt,
                                                 const float* __restrict__ bias,
                                                 const float* __restrict__ ls,
                                                 float* __restrict__ out)
{
    __shared__ __align__(16) char At[8192];
    __shared__ __align__(16) char Bl[8192];
    const int t = threadIdx.x;
    const int wid = t >> 6, lane = t & 63;
    const int wr = wid >> 1, wc = wid & 1;
    const int ln = lane & 15, kg = lane >> 4;

    const int f   = blockIdx.x;
    const int xcd = f & 7, jj = f >> 3;
    const int byx = (gridDim.x >> 3) / 2;
    const int by  = xcd * byx + jj / 2;
    const int bx  = jj & 1;

    const char* Ab = (const char*)A  + (size_t)by * 128 * 1024;
    const char* Bb = (const char*)Bt + (size_t)bx * 128 * 1024;

    const f32x4 fz = {0.f, 0.f, 0.f, 0.f};
    f32x4 acc[4][4];
#pragma unroll
    for (int i = 0; i < 4; ++i)
#pragma unroll
        for (int j = 0; j < 4; ++j) acc[i][j] = fz;

#pragma unroll
    for (int s = 0; s < 16; ++s) {
        const size_t kb = (size_t)s * 64;
#pragma unroll
        for (int i = 0; i < 2; ++i) {
            int p   = (i * 256 + t) * 16;
            int row = p >> 6;
            int off = (p & 63) ^ ((row & 3) << 4);
            __builtin_amdgcn_global_load_lds((global_cv*)(Ab + (size_t)row * 1024 + kb + off),
                                             (lds_v*)(At + p), 16, 0, 0);
            __builtin_amdgcn_global_load_lds((global_cv*)(Bb + (size_t)row * 1024 + kb + off),
                                             (lds_v*)(Bl + p), 16, 0, 0);
        }
        __syncthreads();
#pragma unroll
        for (int kk = 0; kk < 2; ++kk) {
            i64_t av[4], bv[4];
#pragma unroll
            for (int mt = 0; mt < 4; ++mt) {
                int row = wr * 64 + mt * 16 + ln;
                av[mt] = *(const i64_t*)(At + row * 64 + ((kk * 32 + kg * 8) ^ ((row & 3) << 4)));
            }
#pragma unroll
            for (int nt = 0; nt < 4; ++nt) {
                int row = wc * 64 + nt * 16 + ln;
                bv[nt] = *(const i64_t*)(Bl + row * 64 + ((kk * 32 + kg * 8) ^ ((row & 3) << 4)));
            }
#pragma unroll
            for (int mt = 0; mt < 4; ++mt)
#pragma unroll
                for (int nt = 0; nt < 4; ++nt)
                    acc[mt][nt] = __builtin_amdgcn_mfma_f32_16x16x32_fp8_fp8(bv[nt], av[mt], acc[mt][nt], 0, 0, 0);
        }
        __syncthreads();
    }

#pragma unroll
    for (int mt = 0; mt < 4; ++mt) {
        const int row = by * 128 + wr * 64 + mt * 16 + ln;
#pragma unroll
        for (int nt = 0; nt < 4; ++nt) {
            const int colb = bx * 128 + wc * 64 + nt * 16 + kg * 4;
            const f32x4 a = acc[mt][nt];
            const float4 b4 = *(const float4*)(bias + colb);
            const float4 l4 = *(const float4*)(ls + colb);
            size_t idx = (size_t)row * 256 + colb;
            float4 cur = *(const float4*)(out + idx);
            cur.x += l4.x * (a[0] * 0.00390625f + b4.x);
            cur.y += l4.y * (a[1] * 0.00390625f + b4.y);
            cur.z += l4.z * (a[2] * 0.00390625f + b4.z);
            cur.w += l4.w * (a[3] * 0.00390625f + b4.w);
            *(float4*)(out + idx) = cur;
        }
    }
}

// ---------------- fused per-window attention: per-mt pipeline (r18, unchanged) ----------------
__global__ __launch_bounds__(256) void attn_k(const bf16_t* __restrict__ qkvt,
                                              bf16_t* __restrict__ out)
{
    __shared__ bf16_t Plds[4 * 2 * 1408];   // per wave: 2 x [16][88]
    const int t = threadIdx.x, wid = t >> 6, lane = t & 63;
    const int ln = lane & 15, kg = lane >> 4;
    bf16_t* P0 = &Plds[wid * 2816];
    bf16_t* P1 = P0 + 1408;
    const int b = blockIdx.x;
    const int w = b >> 1;
    const int h = (b & 1) * 4 + wid;
    const float SCALE = 0.17677669529663689f;

    const bf16_t* Qb = qkvt + (size_t)w * 61440 + (size_t)h * 7680;
    const bf16_t* Kb = Qb + 2560;
    const bf16_t* Vb = Qb + 5120;

    bf16x8 kb[5];
#pragma unroll
    for (int nt = 0; nt < 5; ++nt)
        kb[nt] = *(const bf16x8*)(Kb + (nt * 16 + ln) * 32 + kg * 8);

#pragma unroll
    for (int mt = 0; mt < 5; ++mt) {
        bf16x8 qa = *(const bf16x8*)(Qb + (mt * 16 + ln) * 32 + kg * 8);
        f32x4 S[5];
#pragma unroll
        for (int nt = 0; nt < 5; ++nt) {
            f32x4 z = {0.f, 0.f, 0.f, 0.f};
            S[nt] = __builtin_amdgcn_mfma_f32_16x16x32_bf16(qa, kb[nt], z, 0, 0, 0);
        }
#pragma unroll
        for (int r = 0; r < 4; ++r) {
            float mx = S[0][r];
#pragma unroll
            for (int nt = 1; nt < 5; ++nt) mx = fmaxf(mx, S[nt][r]);
            mx = fmaxf(mx, __shfl_xor(mx, 1, 64));
            mx = fmaxf(mx, __shfl_xor(mx, 2, 64));
            mx = fmaxf(mx, __shfl_xor(mx, 4, 64));
            mx = fmaxf(mx, __shfl_xor(mx, 8, 64));
            float sum = 0.f;
#pragma unroll
            for (int nt = 0; nt < 5; ++nt) {
                float e = __expf((S[nt][r] - mx) * SCALE);
                S[nt][r] = e;
                sum += e;
            }
            sum += __shfl_xor(sum, 1, 64);
            sum += __shfl_xor(sum, 2, 64);
            sum += __shfl_xor(sum, 4, 64);
            sum += __shfl_xor(sum, 8, 64);
            float inv = 1.f / sum;
#pragma unroll
            for (int nt = 0; nt < 5; ++nt) S[nt][r] *= inv;
        }
        bf16_t* Pc = (mt & 1) ? P1 : P0;
#pragma unroll
        for (int nt = 0; nt < 5; ++nt)
#pragma unroll
            for (int r = 0; r < 4; ++r)
                Pc[(kg * 4 + r) * 88 + nt * 16 + ln] = (bf16_t)S[nt][r];
        f32x4 O[2];
        O[0] = (f32x4){0.f, 0.f, 0.f, 0.f};
        O[1] = (f32x4){0.f, 0.f, 0.f, 0.f};
#pragma unroll
        for (int nt2 = 0; nt2 < 2; ++nt2) {
#pragma unroll
            for (int kt = 0; kt < 3; ++kt) {
                const bool dead = (kt == 2) && (kg >= 2);
                int off = kt * 32 + kg * 8;
                if (off >= 80) off = 0;
                bf16x8 bv = *(const bf16x8*)(Vb + (nt2 * 16 + ln) * 80 + off);
                if (dead) {
#pragma unroll
                    for (int j = 0; j < 8; ++j) bv[j] = (bf16_t)0.f;
                }
                int cb = kt * 32 + kg * 8;
                if (cb >= 80) cb = 0;
                bf16x8 av = *(const bf16x8*)(Pc + ln * 88 + cb);
                O[nt2] = __builtin_amdgcn_mfma_f32_16x16x32_bf16(av, bv, O[nt2], 0, 0, 0);
            }
        }
#pragma unroll
        for (int nt2 = 0; nt2 < 2; ++nt2)
#pragma unroll
            for (int r = 0; r < 4; ++r) {
                int n = mt * 16 + kg * 4 + r;
                out[((size_t)w * 80 + n) * 256 + h * 32 + nt2 * 16 + ln] = (bf16_t)O[nt2][r];
            }
    }
}

// ---------------- launch ----------------
extern "C" void kernel_launch(void* const* d_in, const int* in_sizes, int n_in,
                              void* d_out, int out_size, void* d_ws, size_t ws_size,
                              hipStream_t stream)
{
    (void)in_sizes; (void)n_in; (void)out_size; (void)ws_size;
    const float* x     = (const float*)d_in[0];
    const float* n1g   = (const float*)d_in[1];
    const float* n1b   = (const float*)d_in[2];
    const float* qkvw  = (const float*)d_in[3];
    const float* qkvb  = (const float*)d_in[4];
    const float* projw = (const float*)d_in[5];
    const float* projb = (const float*)d_in[6];
    const float* ls1   = (const float*)d_in[7];
    const float* n2g   = (const float*)d_in[8];
    const float* n2b   = (const float*)d_in[9];
    const float* fc1w  = (const float*)d_in[10];
    const float* fc1b  = (const float*)d_in[11];
    const float* fc2w  = (const float*)d_in[12];
    const float* fc2b  = (const float*)d_in[13];
    const float* ls2   = (const float*)d_in[14];
    float* out = (float*)d_out;

    // ws (bytes): [0,42MB) actA: ln1p -> attno -> ln2 (sequential reuse)
    //             [42,210MB) big: qkvt 126MB -> h1 fp8 84MB (sequential reuse)
    //             [210MB,..) weights: bf16 ~1MB + fp8 fc2w 256KB
    char* ws = (char*)d_ws;
    bf16_t* actA   = (bf16_t*)(ws);
    bf16_t* qkvt   = (bf16_t*)(ws + 41943040ull);
    unsigned char* h1f8 = (unsigned char*)(ws + 41943040ull);
    bf16_t* wbuf   = (bf16_t*)(ws + 209715200ull);
    bf16_t* qkvwt  = wbuf;                          // [768][256]
    bf16_t* projwt = qkvwt + 768 * 256;             // [256][256]
    bf16_t* fc1wt  = projwt + 256 * 256;            // [1024][256]
    unsigned char* fc2w8 = (unsigned char*)(fc1wt + 1024 * 256);   // fp8 [256][1024]

    wconv_k<<<768,  256, 0, stream>>>(qkvw,  qkvwt, 768, 256);
    wconv_k<<<256,  256, 0, stream>>>(projw, projwt, 256, 256);
    wconv_k<<<1024, 256, 0, stream>>>(fc1w,  fc1wt, 1024, 256);
    wconv8_k<<<256, 256, 0, stream>>>(fc2w, fc2w8);

    ln_k<1><<<20480, 256, 0, stream>>>(x, n1g, n1b, actA);
    gq_k<<<7680, 256, 0, stream>>>(actA, qkvwt, qkvb, qkvt);              // 640 x 12
    attn_k<<<2048, 256, 0, stream>>>(qkvt, actA);
    gp_k<<<2560, 256, 0, stream>>>(actA, projwt, projb, x, ls1, out);     // 640 x 4
    ln_k<0><<<20480, 256, 0, stream>>>(out, n2g, n2b, actA);
    g1_k<<<10240, 256, 0, stream>>>(actA, fc1wt, fc1b, h1f8);             // 640 x 16
    g2f8_k<<<1280, 256, 0, stream>>>(h1f8, fc2w8, fc2b, ls2, out);        // 640 x 2
}

// Round 21
// 386.057 us; speedup vs baseline: 1.0779x; 1.0779x over previous
//
#include <hip/hip_runtime.h>
#include <hip/hip_bf16.h>
#include <stdint.h>
#include <math.h>

typedef __bf16 bf16_t;
typedef __bf16 bf16x8 __attribute__((ext_vector_type(8)));
typedef __bf16 bf16x4 __attribute__((ext_vector_type(4)));
typedef float  f32x4  __attribute__((ext_vector_type(4)));
typedef long long i64_t;

typedef __attribute__((address_space(1))) const void global_cv;
typedef __attribute__((address_space(3))) void lds_v;

// Problem constants: B=16,H=64,W=80,C=256; GH=8,GW=10; heads=8,DH=32; INNER=1024
// qkvt layout (per window w, head h; elem offsets):
//   base = w*61440 + h*7680 ; Q[tok][32] at +0 ; K[tok][32] at +2560 ; V^T[32][80] at +5120

__device__ __forceinline__ int map_p_to_g(int p) {
    int w = p / 80, n = p - w * 80;
    int b  = w >> 6, h2 = (w >> 3) & 7, w2 = w & 7;
    int gh = n / 10, gw = n - gh * 10;
    return b * 5120 + (gh * 8 + h2) * 80 + (gw * 8 + w2);
}

// XOR swizzle for 128-B LDS rows: bits 4-6 ^= bits 7-9 (involution, keeps 16B align)
__device__ __forceinline__ int swz128(int b) { return b ^ (((b >> 7) & 7) << 4); }

// ---------------- weight convert+transpose: fp32 [K][N] -> bf16 [N][K] ----------------
__global__ __launch_bounds__(256) void wconv_k(const float* __restrict__ in,
                                               bf16_t* __restrict__ out, int N, int K)
{
    int i = blockIdx.x * 256 + threadIdx.x;
    int n = i / K, k = i - n * K;
    out[i] = (bf16_t)in[(size_t)k * N + n];
}

// ---------------- fc2 weight convert: fp32 [1024][256] -> fp8 e4m3 [256][1024], x16 ----------------
__global__ __launch_bounds__(256) void wconv8_k(const float* __restrict__ in,
                                                unsigned char* __restrict__ out)
{
    int c  = blockIdx.x * 256 + threadIdx.x;
    int n  = (c * 4) >> 10;
    int k0 = (c * 4) & 1023;
    float g0 = 16.f * in[(size_t)(k0 + 0) * 256 + n];
    float g1 = 16.f * in[(size_t)(k0 + 1) * 256 + n];
    float g2 = 16.f * in[(size_t)(k0 + 2) * 256 + n];
    float g3 = 16.f * in[(size_t)(k0 + 3) * 256 + n];
    int pk = __builtin_amdgcn_cvt_pk_fp8_f32(g0, g1, 0, false);
    pk     = __builtin_amdgcn_cvt_pk_fp8_f32(g2, g3, pk, true);
    *(int*)(out + (size_t)c * 4) = pk;
}

// ---------------- LayerNorm (one wave per row), optional partition permute ----------------
template <int PERM>
__global__ __launch_bounds__(256) void ln_k(const float* __restrict__ in,
                                            const float* __restrict__ gg,
                                            const float* __restrict__ bb,
                                            bf16_t* __restrict__ o)
{
    int row  = blockIdx.x * 4 + (threadIdx.x >> 6);
    int lane = threadIdx.x & 63;
    const float4 xv = *(const float4*)(in + (size_t)row * 256 + lane * 4);
    float s = xv.x + xv.y + xv.z + xv.w;
#pragma unroll
    for (int m = 1; m < 64; m <<= 1) s += __shfl_xor(s, m, 64);
    float mean = s * (1.f / 256.f);
    float d0 = xv.x - mean, d1 = xv.y - mean, d2 = xv.z - mean, d3 = xv.w - mean;
    float v = d0 * d0 + d1 * d1 + d2 * d2 + d3 * d3;
#pragma unroll
    for (int m = 1; m < 64; m <<= 1) v += __shfl_xor(v, m, 64);
    float rstd = rsqrtf(v * (1.f / 256.f) + 1e-5f);
    const float4 gv = *(const float4*)(gg + lane * 4);
    const float4 bv = *(const float4*)(bb + lane * 4);
    int orow = row;
    if (PERM) {
        int b = row / 5120, r1 = row - b * 5120;
        int h = r1 / 80, wv = r1 - h * 80;
        int gh = h >> 3, h2 = h & 7, gw = wv >> 3, w2 = wv & 7;
        orow = ((b * 8 + h2) * 8 + w2) * 80 + gh * 10 + gw;
    }
    bf16x4 ov;
    ov[0] = (bf16_t)(d0 * rstd * gv.x + bv.x);
    ov[1] = (bf16_t)(d1 * rstd * gv.y + bv.y);
    ov[2] = (bf16_t)(d2 * rstd * gv.z + bv.z);
    ov[3] = (bf16_t)(d3 * rstd * gv.w + bv.w);
    *(bf16x4*)(o + (size_t)orow * 256 + lane * 4) = ov;
}

// ---------------- 128x64-tile MFMA GEMM, high-residency (6 blocks/CU target) ----------------
// Wave tile 32x64 (acc[2][4] = 32 AGPR; ~80 total regs -> 6 waves/SIMD). Block = 4
// row-stacked waves; LDS 24KB (At 16 + Bl 8). Proven swz128 both-sides staging,
// swapped-operand D^T epilogue, XCD-bijective grid. Runtime N/K (r20 showed the
// templated full-unroll variant regresses via lost L2 reuse timing).
// EPI 0: qkvt scatter; EPI 1: fp32 x[g]+ls*(acc+b) grid-reverse; EPI 2: fp8 16*gelu
template <int EPI, int NBX>
__device__ __forceinline__ void gemm_body(const bf16_t* __restrict__ A,
                                          const bf16_t* __restrict__ Bt,
                                          const float* __restrict__ bias,
                                          const float* __restrict__ xres,
                                          const float* __restrict__ ls,
                                          void* __restrict__ outp,
                                          int N, int K)
{
    __shared__ bf16_t At[128 * 64];   // 16 KB: 128 rows x 128 B
    __shared__ bf16_t Bl[64 * 64];    //  8 KB:  64 rows x 128 B
    const int t = threadIdx.x;
    const int wid = t >> 6, lane = t & 63;
    const int ln = lane & 15, kg = lane >> 4;

    const int f   = blockIdx.x;
    const int xcd = f & 7, jj = f >> 3;
    const int byx = (gridDim.x >> 3) / NBX;
    const int by  = xcd * byx + jj / NBX;
    const int bx  = jj % NBX;

    const size_t Kb = (size_t)K * 2;
    const char* Ab = (const char*)(A  + (size_t)by * 128 * K);
    const char* Bb = (const char*)(Bt + (size_t)bx * 64 * K);
    char* AtB = (char*)At;
    char* BlB = (char*)Bl;

    // hoisted staging maps
    int spa[4], sra[4], soa[4];
#pragma unroll
    for (int i = 0; i < 4; ++i) {
        spa[i] = (i * 256 + t) * 16;
        sra[i] = spa[i] >> 7;
        soa[i] = (spa[i] & 127) ^ ((sra[i] & 7) << 4);
    }
    int spb[2], srb[2], sob[2];
#pragma unroll
    for (int i = 0; i < 2; ++i) {
        spb[i] = (i * 256 + t) * 16;
        srb[i] = spb[i] >> 7;
        sob[i] = (spb[i] & 127) ^ ((srb[i] & 7) << 4);
    }

    const f32x4 fz = {0.f, 0.f, 0.f, 0.f};
    f32x4 acc[2][4];
#pragma unroll
    for (int i = 0; i < 2; ++i)
#pragma unroll
        for (int j = 0; j < 4; ++j) acc[i][j] = fz;

    const int nsteps = K >> 6;

    for (int s = 0; s < nsteps; ++s) {
        const size_t kb = (size_t)s * 128;
#pragma unroll
        for (int i = 0; i < 4; ++i)
            __builtin_amdgcn_global_load_lds((global_cv*)(Ab + (size_t)sra[i] * Kb + kb + soa[i]),
                                             (lds_v*)(AtB + spa[i]), 16, 0, 0);
#pragma unroll
        for (int i = 0; i < 2; ++i)
            __builtin_amdgcn_global_load_lds((global_cv*)(Bb + (size_t)srb[i] * Kb + kb + sob[i]),
                                             (lds_v*)(BlB + spb[i]), 16, 0, 0);
        __syncthreads();
#pragma unroll
        for (int kk = 0; kk < 2; ++kk) {
            bf16x8 av[2], bv[4];
#pragma unroll
            for (int mt = 0; mt < 2; ++mt) {
                int row = wid * 32 + mt * 16 + ln;
                av[mt] = *(const bf16x8*)(AtB + swz128(row * 128 + kk * 64 + kg * 16));
            }
#pragma unroll
            for (int nt = 0; nt < 4; ++nt) {
                int row = nt * 16 + ln;
                bv[nt] = *(const bf16x8*)(BlB + swz128(row * 128 + kk * 64 + kg * 16));
            }
            // swapped operands: D^T -> our row = ln, our cols = kg*4+r
#pragma unroll
            for (int mt = 0; mt < 2; ++mt)
#pragma unroll
                for (int nt = 0; nt < 4; ++nt)
                    acc[mt][nt] = __builtin_amdgcn_mfma_f32_16x16x32_bf16(bv[nt], av[mt], acc[mt][nt], 0, 0, 0);
        }
        __syncthreads();
    }

#pragma unroll
    for (int mt = 0; mt < 2; ++mt) {
        const int row = by * 128 + wid * 32 + mt * 16 + ln;
        const int wno = row / 80, tok = row - wno * 80;   // EPI 0
#pragma unroll
        for (int nt = 0; nt < 4; ++nt) {
            const int colb = bx * 64 + nt * 16 + kg * 4;
            const f32x4 a = acc[mt][nt];
            const float4 b4 = *(const float4*)(bias + colb);
            if constexpr (EPI == 0) {
                bf16_t* o = (bf16_t*)outp;
                const int typ = colb >> 8, h = (colb >> 5) & 7, d0 = colb & 31;
                const size_t base = (size_t)wno * 61440 + (size_t)h * 7680;
                if (typ < 2) {
                    bf16x4 ov;
                    ov[0] = (bf16_t)(a[0] + b4.x); ov[1] = (bf16_t)(a[1] + b4.y);
                    ov[2] = (bf16_t)(a[2] + b4.z); ov[3] = (bf16_t)(a[3] + b4.w);
                    *(bf16x4*)(o + base + typ * 2560 + tok * 32 + d0) = ov;
                } else {
#pragma unroll
                    for (int r = 0; r < 4; ++r)
                        o[base + 5120 + (size_t)(d0 + r) * 80 + tok] =
                            (bf16_t)(a[r] + ((const float*)&b4)[r]);
                }
            } else if constexpr (EPI == 1) {
                const float4 l4 = *(const float4*)(ls + colb);
                float* o = (float*)outp;
                int g = map_p_to_g(row);
                size_t idx = (size_t)g * 256 + colb;
                float4 xr = *(const float4*)(xres + idx);
                float4 r4;
                r4.x = xr.x + l4.x * (a[0] + b4.x);
                r4.y = xr.y + l4.y * (a[1] + b4.y);
                r4.z = xr.z + l4.z * (a[2] + b4.z);
                r4.w = xr.w + l4.w * (a[3] + b4.w);
                *(float4*)(o + idx) = r4;
            } else {   // fc1 -> fp8 h1 (x16)
                unsigned char* o = (unsigned char*)outp;
                float g4[4];
#pragma unroll
                for (int r = 0; r < 4; ++r) {
                    float u2 = a[r] + ((const float*)&b4)[r];
                    float e = __expf(-1.702f * u2);
                    g4[r] = (16.f * u2) * __builtin_amdgcn_rcpf(1.f + e);
                }
                int pk = __builtin_amdgcn_cvt_pk_fp8_f32(g4[0], g4[1], 0, false);
                pk     = __builtin_amdgcn_cvt_pk_fp8_f32(g4[2], g4[3], pk, true);
                *(int*)(o + (size_t)row * N + colb) = pk;
            }
        }
    }
}

__global__ __launch_bounds__(256, 6) void gq_k(const bf16_t* A, const bf16_t* Bt, const float* bias,
                                               void* outp, int N, int K)
{ gemm_body<0, 12>(A, Bt, bias, nullptr, nullptr, outp, N, K); }

__global__ __launch_bounds__(256, 6) void gp_k(const bf16_t* A, const bf16_t* Bt, const float* bias,
                                               const float* xres, const float* ls, void* outp, int N, int K)
{ gemm_body<1, 4>(A, Bt, bias, xres, ls, outp, N, K); }

__global__ __launch_bounds__(256, 6) void g1_k(const bf16_t* A, const bf16_t* Bt, const float* bias,
                                               void* outp, int N, int K)
{ gemm_body<2, 16>(A, Bt, bias, nullptr, nullptr, outp, N, K); }

// ---------------- fc2 GEMM in fp8 (r15, unchanged) ----------------
__global__ __launch_bounds__(256, 4) void g2f8_k(const unsigned char* __restrict__ A,
                                                 const unsigned char* __restrict__ Bt,
                                                 const float* __restrict__ bias,
                                                 const float* __restrict__ ls,
                                                 float* __restrict__ out)
{
    __shared__ __align__(16) char At[8192];
    __shared__ __align__(16) char Bl[8192];
    const int t = threadIdx.x;
    const int wid = t >> 6, lane = t & 63;
    const int wr = wid >> 1, wc = wid & 1;
    const int ln = lane & 15, kg = lane >> 4;

    const int f   = blockIdx.x;
    const int xcd = f & 7, jj = f >> 3;
    const int byx = (gridDim.x >> 3) / 2;
    const int by  = xcd * byx + jj / 2;
    const int bx  = jj & 1;

    const char* Ab = (const char*)A  + (size_t)by * 128 * 1024;
    const char* Bb = (const char*)Bt + (size_t)bx * 128 * 1024;

    const f32x4 fz = {0.f, 0.f, 0.f, 0.f};
    f32x4 acc[4][4];
#pragma unroll
    for (int i = 0; i < 4; ++i)
#pragma unroll
        for (int j = 0; j < 4; ++j) acc[i][j] = fz;

    for (int s = 0; s < 16; ++s) {
        const size_t kb = (size_t)s * 64;
#pragma unroll
        for (int i = 0; i < 2; ++i) {
            int p   = (i * 256 + t) * 16;
            int row = p >> 6;
            int off = (p & 63) ^ ((row & 3) << 4);
            __builtin_amdgcn_global_load_lds((global_cv*)(Ab + (size_t)row * 1024 + kb + off),
                                             (lds_v*)(At + p), 16, 0, 0);
            __builtin_amdgcn_global_load_lds((global_cv*)(Bb + (size_t)row * 1024 + kb + off),
                                             (lds_v*)(Bl + p), 16, 0, 0);
        }
        __syncthreads();
#pragma unroll
        for (int kk = 0; kk < 2; ++kk) {
            i64_t av[4], bv[4];
#pragma unroll
            for (int mt = 0; mt < 4; ++mt) {
                int row = wr * 64 + mt * 16 + ln;
                av[mt] = *(const i64_t*)(At + row * 64 + ((kk * 32 + kg * 8) ^ ((row & 3) << 4)));
            }
#pragma unroll
            for (int nt = 0; nt < 4; ++nt) {
                int row = wc * 64 + nt * 16 + ln;
                bv[nt] = *(const i64_t*)(Bl + row * 64 + ((kk * 32 + kg * 8) ^ ((row & 3) << 4)));
            }
#pragma unroll
            for (int mt = 0; mt < 4; ++mt)
#pragma unroll
                for (int nt = 0; nt < 4; ++nt)
                    acc[mt][nt] = __builtin_amdgcn_mfma_f32_16x16x32_fp8_fp8(bv[nt], av[mt], acc[mt][nt], 0, 0, 0);
        }
        __syncthreads();
    }

#pragma unroll
    for (int mt = 0; mt < 4; ++mt) {
        const int row = by * 128 + wr * 64 + mt * 16 + ln;
#pragma unroll
        for (int nt = 0; nt < 4; ++nt) {
            const int colb = bx * 128 + wc * 64 + nt * 16 + kg * 4;
            const f32x4 a = acc[mt][nt];
            const float4 b4 = *(const float4*)(bias + colb);
            const float4 l4 = *(const float4*)(ls + colb);
            size_t idx = (size_t)row * 256 + colb;
            float4 cur = *(const float4*)(out + idx);
            cur.x += l4.x * (a[0] * 0.00390625f + b4.x);
            cur.y += l4.y * (a[1] * 0.00390625f + b4.y);
            cur.z += l4.z * (a[2] * 0.00390625f + b4.z);
            cur.w += l4.w * (a[3] * 0.00390625f + b4.w);
            *(float4*)(out + idx) = cur;
        }
    }
}

// ---------------- fused per-window attention: per-mt pipeline (r18, unchanged) ----------------
__global__ __launch_bounds__(256) void attn_k(const bf16_t* __restrict__ qkvt,
                                              bf16_t* __restrict__ out)
{
    __shared__ bf16_t Plds[4 * 2 * 1408];   // per wave: 2 x [16][88]
    const int t = threadIdx.x, wid = t >> 6, lane = t & 63;
    const int ln = lane & 15, kg = lane >> 4;
    bf16_t* P0 = &Plds[wid * 2816];
    bf16_t* P1 = P0 + 1408;
    const int b = blockIdx.x;
    const int w = b >> 1;
    const int h = (b & 1) * 4 + wid;
    const float SCALE = 0.17677669529663689f;

    const bf16_t* Qb = qkvt + (size_t)w * 61440 + (size_t)h * 7680;
    const bf16_t* Kb = Qb + 2560;
    const bf16_t* Vb = Qb + 5120;

    bf16x8 kb[5];
#pragma unroll
    for (int nt = 0; nt < 5; ++nt)
        kb[nt] = *(const bf16x8*)(Kb + (nt * 16 + ln) * 32 + kg * 8);

#pragma unroll
    for (int mt = 0; mt < 5; ++mt) {
        bf16x8 qa = *(const bf16x8*)(Qb + (mt * 16 + ln) * 32 + kg * 8);
        f32x4 S[5];
#pragma unroll
        for (int nt = 0; nt < 5; ++nt) {
            f32x4 z = {0.f, 0.f, 0.f, 0.f};
            S[nt] = __builtin_amdgcn_mfma_f32_16x16x32_bf16(qa, kb[nt], z, 0, 0, 0);
        }
#pragma unroll
        for (int r = 0; r < 4; ++r) {
            float mx = S[0][r];
#pragma unroll
            for (int nt = 1; nt < 5; ++nt) mx = fmaxf(mx, S[nt][r]);
            mx = fmaxf(mx, __shfl_xor(mx, 1, 64));
            mx = fmaxf(mx, __shfl_xor(mx, 2, 64));
            mx = fmaxf(mx, __shfl_xor(mx, 4, 64));
            mx = fmaxf(mx, __shfl_xor(mx, 8, 64));
            float sum = 0.f;
#pragma unroll
            for (int nt = 0; nt < 5; ++nt) {
                float e = __expf((S[nt][r] - mx) * SCALE);
                S[nt][r] = e;
                sum += e;
            }
            sum += __shfl_xor(sum, 1, 64);
            sum += __shfl_xor(sum, 2, 64);
            sum += __shfl_xor(sum, 4, 64);
            sum += __shfl_xor(sum, 8, 64);
            float inv = 1.f / sum;
#pragma unroll
            for (int nt = 0; nt < 5; ++nt) S[nt][r] *= inv;
        }
        bf16_t* Pc = (mt & 1) ? P1 : P0;
#pragma unroll
        for (int nt = 0; nt < 5; ++nt)
#pragma unroll
            for (int r = 0; r < 4; ++r)
                Pc[(kg * 4 + r) * 88 + nt * 16 + ln] = (bf16_t)S[nt][r];
        f32x4 O[2];
        O[0] = (f32x4){0.f, 0.f, 0.f, 0.f};
        O[1] = (f32x4){0.f, 0.f, 0.f, 0.f};
#pragma unroll
        for (int nt2 = 0; nt2 < 2; ++nt2) {
#pragma unroll
            for (int kt = 0; kt < 3; ++kt) {
                const bool dead = (kt == 2) && (kg >= 2);
                int off = kt * 32 + kg * 8;
                if (off >= 80) off = 0;
                bf16x8 bv = *(const bf16x8*)(Vb + (nt2 * 16 + ln) * 80 + off);
                if (dead) {
#pragma unroll
                    for (int j = 0; j < 8; ++j) bv[j] = (bf16_t)0.f;
                }
                int cb = kt * 32 + kg * 8;
                if (cb >= 80) cb = 0;
                bf16x8 av = *(const bf16x8*)(Pc + ln * 88 + cb);
                O[nt2] = __builtin_amdgcn_mfma_f32_16x16x32_bf16(av, bv, O[nt2], 0, 0, 0);
            }
        }
#pragma unroll
        for (int nt2 = 0; nt2 < 2; ++nt2)
#pragma unroll
            for (int r = 0; r < 4; ++r) {
                int n = mt * 16 + kg * 4 + r;
                out[((size_t)w * 80 + n) * 256 + h * 32 + nt2 * 16 + ln] = (bf16_t)O[nt2][r];
            }
    }
}

// ---------------- launch ----------------
extern "C" void kernel_launch(void* const* d_in, const int* in_sizes, int n_in,
                              void* d_out, int out_size, void* d_ws, size_t ws_size,
                              hipStream_t stream)
{
    (void)in_sizes; (void)n_in; (void)out_size; (void)ws_size;
    const float* x     = (const float*)d_in[0];
    const float* n1g   = (const float*)d_in[1];
    const float* n1b   = (const float*)d_in[2];
    const float* qkvw  = (const float*)d_in[3];
    const float* qkvb  = (const float*)d_in[4];
    const float* projw = (const float*)d_in[5];
    const float* projb = (const float*)d_in[6];
    const float* ls1   = (const float*)d_in[7];
    const float* n2g   = (const float*)d_in[8];
    const float* n2b   = (const float*)d_in[9];
    const float* fc1w  = (const float*)d_in[10];
    const float* fc1b  = (const float*)d_in[11];
    const float* fc2w  = (const float*)d_in[12];
    const float* fc2b  = (const float*)d_in[13];
    const float* ls2   = (const float*)d_in[14];
    float* out = (float*)d_out;

    // ws (bytes): [0,42MB) actA: ln1p -> attno -> ln2 (sequential reuse)
    //             [42,210MB) big: qkvt 126MB -> h1 fp8 84MB (sequential reuse)
    //             [210MB,..) weights: bf16 ~1MB + fp8 fc2w 256KB
    char* ws = (char*)d_ws;
    bf16_t* actA   = (bf16_t*)(ws);
    bf16_t* qkvt   = (bf16_t*)(ws + 41943040ull);
    unsigned char* h1f8 = (unsigned char*)(ws + 41943040ull);
    bf16_t* wbuf   = (bf16_t*)(ws + 209715200ull);
    bf16_t* qkvwt  = wbuf;                          // [768][256]
    bf16_t* projwt = qkvwt + 768 * 256;             // [256][256]
    bf16_t* fc1wt  = projwt + 256 * 256;            // [1024][256]
    unsigned char* fc2w8 = (unsigned char*)(fc1wt + 1024 * 256);   // fp8 [256][1024]

    wconv_k<<<768,  256, 0, stream>>>(qkvw,  qkvwt, 768, 256);
    wconv_k<<<256,  256, 0, stream>>>(projw, projwt, 256, 256);
    wconv_k<<<1024, 256, 0, stream>>>(fc1w,  fc1wt, 1024, 256);
    wconv8_k<<<256, 256, 0, stream>>>(fc2w, fc2w8);

    ln_k<1><<<20480, 256, 0, stream>>>(x, n1g, n1b, actA);
    gq_k<<<7680, 256, 0, stream>>>(actA, qkvwt, qkvb, qkvt, 768, 256);    // 640 x 12
    attn_k<<<2048, 256, 0, stream>>>(qkvt, actA);
    gp_k<<<2560, 256, 0, stream>>>(actA, projwt, projb, x, ls1, out, 256, 256);   // 640 x 4
    ln_k<0><<<20480, 256, 0, stream>>>(out, n2g, n2b, actA);
    g1_k<<<10240, 256, 0, stream>>>(actA, fc1wt, fc1b, h1f8, 1024, 256);  // 640 x 16
    g2f8_k<<<1280, 256, 0, stream>>>(h1f8, fc2w8, fc2b, ls2, out);        // 640 x 2
}

// Round 22
// 383.926 us; speedup vs baseline: 1.0838x; 1.0056x over previous
//
#include <hip/hip_runtime.h>
#include <hip/hip_bf16.h>
#include <stdint.h>
#include <math.h>

typedef __bf16 bf16_t;
typedef __bf16 bf16x8 __attribute__((ext_vector_type(8)));
typedef __bf16 bf16x4 __attribute__((ext_vector_type(4)));
typedef float  f32x4  __attribute__((ext_vector_type(4)));
typedef long long i64_t;

typedef __attribute__((address_space(1))) const void global_cv;
typedef __attribute__((address_space(3))) void lds_v;

// Problem constants: B=16,H=64,W=80,C=256; GH=8,GW=10; heads=8,DH=32; INNER=1024
// qkvt layout (per window w, head h; elem offsets):
//   base = w*61440 + h*7680 ; Q[tok][32] at +0 ; K[tok][32] at +2560 ; V^T[32][80] at +5120
// h1t layout (fp8, x16): element (row, c) at (c>>6)*5242880 + row*64 + (c&63)
//   -> g1 writes a dense 1KB window per wave; g2f8 stages one contiguous 8KB block/step.

__device__ __forceinline__ int map_p_to_g(int p) {
    int w = p / 80, n = p - w * 80;
    int b  = w >> 6, h2 = (w >> 3) & 7, w2 = w & 7;
    int gh = n / 10, gw = n - gh * 10;
    return b * 5120 + (gh * 8 + h2) * 80 + (gw * 8 + w2);
}

// XOR swizzle for 128-B LDS rows: bits 4-6 ^= bits 7-9 (involution, keeps 16B align)
__device__ __forceinline__ int swz128(int b) { return b ^ (((b >> 7) & 7) << 4); }

// ---------------- coalesced weight transpose: fp32 [K][N] -> bf16 [N][K] ----------------
// 64x64 LDS tile (pad 65): both global phases coalesced, both LDS phases conflict-free.
__global__ __launch_bounds__(256) void wconvt_k(const float* __restrict__ in,
                                                bf16_t* __restrict__ out, int N, int K)
{
    __shared__ float tile[64][65];
    const int n0 = blockIdx.x * 64, k0 = blockIdx.y * 64;
    const int tn = threadIdx.x & 63, tr = threadIdx.x >> 6;
#pragma unroll
    for (int i = 0; i < 16; ++i) {
        int k = i * 4 + tr;
        tile[k][tn] = in[(size_t)(k0 + k) * N + n0 + tn];
    }
    __syncthreads();
#pragma unroll
    for (int i = 0; i < 16; ++i) {
        int n = i * 4 + tr;
        out[(size_t)(n0 + n) * K + k0 + tn] = (bf16_t)tile[tn][n];
    }
}

// ---------------- fc2 weight convert: fp32 [1024][256] -> fp8 e4m3 [256][1024], x16 ----------------
__global__ __launch_bounds__(256) void wconv8_k(const float* __restrict__ in,
                                                unsigned char* __restrict__ out)
{
    int c  = blockIdx.x * 256 + threadIdx.x;
    int n  = (c * 4) >> 10;
    int k0 = (c * 4) & 1023;
    float g0 = 16.f * in[(size_t)(k0 + 0) * 256 + n];
    float g1 = 16.f * in[(size_t)(k0 + 1) * 256 + n];
    float g2 = 16.f * in[(size_t)(k0 + 2) * 256 + n];
    float g3 = 16.f * in[(size_t)(k0 + 3) * 256 + n];
    int pk = __builtin_amdgcn_cvt_pk_fp8_f32(g0, g1, 0, false);
    pk     = __builtin_amdgcn_cvt_pk_fp8_f32(g2, g3, pk, true);
    *(int*)(out + (size_t)c * 4) = pk;
}

// ---------------- LayerNorm (one wave per row), optional partition permute ----------------
template <int PERM>
__global__ __launch_bounds__(256) void ln_k(const float* __restrict__ in,
                                            const float* __restrict__ gg,
                                            const float* __restrict__ bb,
                                            bf16_t* __restrict__ o)
{
    int row  = blockIdx.x * 4 + (threadIdx.x >> 6);
    int lane = threadIdx.x & 63;
    const float4 xv = *(const float4*)(in + (size_t)row * 256 + lane * 4);
    float s = xv.x + xv.y + xv.z + xv.w;
#pragma unroll
    for (int m = 1; m < 64; m <<= 1) s += __shfl_xor(s, m, 64);
    float mean = s * (1.f / 256.f);
    float d0 = xv.x - mean, d1 = xv.y - mean, d2 = xv.z - mean, d3 = xv.w - mean;
    float v = d0 * d0 + d1 * d1 + d2 * d2 + d3 * d3;
#pragma unroll
    for (int m = 1; m < 64; m <<= 1) v += __shfl_xor(v, m, 64);
    float rstd = rsqrtf(v * (1.f / 256.f) + 1e-5f);
    const float4 gv = *(const float4*)(gg + lane * 4);
    const float4 bv = *(const float4*)(bb + lane * 4);
    int orow = row;
    if (PERM) {
        int b = row / 5120, r1 = row - b * 5120;
        int h = r1 / 80, wv = r1 - h * 80;
        int gh = h >> 3, h2 = h & 7, gw = wv >> 3, w2 = wv & 7;
        orow = ((b * 8 + h2) * 8 + w2) * 80 + gh * 10 + gw;
    }
    bf16x4 ov;
    ov[0] = (bf16_t)(d0 * rstd * gv.x + bv.x);
    ov[1] = (bf16_t)(d1 * rstd * gv.y + bv.y);
    ov[2] = (bf16_t)(d2 * rstd * gv.z + bv.z);
    ov[3] = (bf16_t)(d3 * rstd * gv.w + bv.w);
    *(bf16x4*)(o + (size_t)orow * 256 + lane * 4) = ov;
}

// ---------------- 128x64-tile MFMA GEMM, high-residency (r19 core) ----------------
// EPI 0: qkvt scatter; EPI 1: fp32 x[g]+ls*(acc+b) grid-reverse; EPI 2: fp8 16*gelu -> h1t
template <int EPI, int NBX>
__device__ __forceinline__ void gemm_body(const bf16_t* __restrict__ A,
                                          const bf16_t* __restrict__ Bt,
                                          const float* __restrict__ bias,
                                          const float* __restrict__ xres,
                                          const float* __restrict__ ls,
                                          void* __restrict__ outp,
                                          int N, int K)
{
    __shared__ bf16_t At[128 * 64];   // 16 KB: 128 rows x 128 B
    __shared__ bf16_t Bl[64 * 64];    //  8 KB:  64 rows x 128 B
    const int t = threadIdx.x;
    const int wid = t >> 6, lane = t & 63;
    const int ln = lane & 15, kg = lane >> 4;

    const int f   = blockIdx.x;
    const int xcd = f & 7, jj = f >> 3;
    const int byx = (gridDim.x >> 3) / NBX;
    const int by  = xcd * byx + jj / NBX;
    const int bx  = jj % NBX;

    const size_t Kb = (size_t)K * 2;
    const char* Ab = (const char*)(A  + (size_t)by * 128 * K);
    const char* Bb = (const char*)(Bt + (size_t)bx * 64 * K);
    char* AtB = (char*)At;
    char* BlB = (char*)Bl;

    int spa[4], sra[4], soa[4];
#pragma unroll
    for (int i = 0; i < 4; ++i) {
        spa[i] = (i * 256 + t) * 16;
        sra[i] = spa[i] >> 7;
        soa[i] = (spa[i] & 127) ^ ((sra[i] & 7) << 4);
    }
    int spb[2], srb[2], sob[2];
#pragma unroll
    for (int i = 0; i < 2; ++i) {
        spb[i] = (i * 256 + t) * 16;
        srb[i] = spb[i] >> 7;
        sob[i] = (spb[i] & 127) ^ ((srb[i] & 7) << 4);
    }

    const f32x4 fz = {0.f, 0.f, 0.f, 0.f};
    f32x4 acc[2][4];
#pragma unroll
    for (int i = 0; i < 2; ++i)
#pragma unroll
        for (int j = 0; j < 4; ++j) acc[i][j] = fz;

    const int nsteps = K >> 6;

    for (int s = 0; s < nsteps; ++s) {
        const size_t kb = (size_t)s * 128;
#pragma unroll
        for (int i = 0; i < 4; ++i)
            __builtin_amdgcn_global_load_lds((global_cv*)(Ab + (size_t)sra[i] * Kb + kb + soa[i]),
                                             (lds_v*)(AtB + spa[i]), 16, 0, 0);
#pragma unroll
        for (int i = 0; i < 2; ++i)
            __builtin_amdgcn_global_load_lds((global_cv*)(Bb + (size_t)srb[i] * Kb + kb + sob[i]),
                                             (lds_v*)(BlB + spb[i]), 16, 0, 0);
        __syncthreads();
#pragma unroll
        for (int kk = 0; kk < 2; ++kk) {
            bf16x8 av[2], bv[4];
#pragma unroll
            for (int mt = 0; mt < 2; ++mt) {
                int row = wid * 32 + mt * 16 + ln;
                av[mt] = *(const bf16x8*)(AtB + swz128(row * 128 + kk * 64 + kg * 16));
            }
#pragma unroll
            for (int nt = 0; nt < 4; ++nt) {
                int row = nt * 16 + ln;
                bv[nt] = *(const bf16x8*)(BlB + swz128(row * 128 + kk * 64 + kg * 16));
            }
            // swapped operands: D^T -> our row = ln, our cols = kg*4+r
#pragma unroll
            for (int mt = 0; mt < 2; ++mt)
#pragma unroll
                for (int nt = 0; nt < 4; ++nt)
                    acc[mt][nt] = __builtin_amdgcn_mfma_f32_16x16x32_bf16(bv[nt], av[mt], acc[mt][nt], 0, 0, 0);
        }
        __syncthreads();
    }

#pragma unroll
    for (int mt = 0; mt < 2; ++mt) {
        const int row = by * 128 + wid * 32 + mt * 16 + ln;
        const int wno = row / 80, tok = row - wno * 80;   // EPI 0
#pragma unroll
        for (int nt = 0; nt < 4; ++nt) {
            const int colb = bx * 64 + nt * 16 + kg * 4;
            const f32x4 a = acc[mt][nt];
            const float4 b4 = *(const float4*)(bias + colb);
            if constexpr (EPI == 0) {
                bf16_t* o = (bf16_t*)outp;
                const int typ = colb >> 8, h = (colb >> 5) & 7, d0 = colb & 31;
                const size_t base = (size_t)wno * 61440 + (size_t)h * 7680;
                if (typ < 2) {
                    bf16x4 ov;
                    ov[0] = (bf16_t)(a[0] + b4.x); ov[1] = (bf16_t)(a[1] + b4.y);
                    ov[2] = (bf16_t)(a[2] + b4.z); ov[3] = (bf16_t)(a[3] + b4.w);
                    *(bf16x4*)(o + base + typ * 2560 + tok * 32 + d0) = ov;
                } else {
#pragma unroll
                    for (int r = 0; r < 4; ++r)
                        o[base + 5120 + (size_t)(d0 + r) * 80 + tok] =
                            (bf16_t)(a[r] + ((const float*)&b4)[r]);
                }
            } else if constexpr (EPI == 1) {
                const float4 l4 = *(const float4*)(ls + colb);
                float* o = (float*)outp;
                int g = map_p_to_g(row);
                size_t idx = (size_t)g * 256 + colb;
                float4 xr = *(const float4*)(xres + idx);
                float4 r4;
                r4.x = xr.x + l4.x * (a[0] + b4.x);
                r4.y = xr.y + l4.y * (a[1] + b4.y);
                r4.z = xr.z + l4.z * (a[2] + b4.z);
                r4.w = xr.w + l4.w * (a[3] + b4.w);
                *(float4*)(o + idx) = r4;
            } else {   // fc1 -> fp8 h1t (x16), tile-major: dense 1KB/wave write window
                unsigned char* o = (unsigned char*)outp;
                float g4[4];
#pragma unroll
                for (int r = 0; r < 4; ++r) {
                    float u2 = a[r] + ((const float*)&b4)[r];
                    float e = __expf(-1.702f * u2);
                    g4[r] = (16.f * u2) * __builtin_amdgcn_rcpf(1.f + e);
                }
                int pk = __builtin_amdgcn_cvt_pk_fp8_f32(g4[0], g4[1], 0, false);
                pk     = __builtin_amdgcn_cvt_pk_fp8_f32(g4[2], g4[3], pk, true);
                *(int*)(o + (size_t)bx * 5242880 + (size_t)row * 64 + nt * 16 + kg * 4) = pk;
            }
        }
    }
}

__global__ __launch_bounds__(256, 6) void gq_k(const bf16_t* A, const bf16_t* Bt, const float* bias,
                                               void* outp, int N, int K)
{ gemm_body<0, 12>(A, Bt, bias, nullptr, nullptr, outp, N, K); }

__global__ __launch_bounds__(256, 6) void gp_k(const bf16_t* A, const bf16_t* Bt, const float* bias,
                                               const float* xres, const float* ls, void* outp, int N, int K)
{ gemm_body<1, 4>(A, Bt, bias, xres, ls, outp, N, K); }

__global__ __launch_bounds__(256, 6) void g1_k(const bf16_t* A, const bf16_t* Bt, const float* bias,
                                               void* outp, int N, int K)
{ gemm_body<2, 16>(A, Bt, bias, nullptr, nullptr, outp, N, K); }

// ---------------- fc2 GEMM in fp8; A = h1t tile-major (contiguous 8KB stage/step) ----------------
__global__ __launch_bounds__(256, 4) void g2f8_k(const unsigned char* __restrict__ A,
                                                 const unsigned char* __restrict__ Bt,
                                                 const float* __restrict__ bias,
                                                 const float* __restrict__ ls,
                                                 float* __restrict__ out)
{
    __shared__ __align__(16) char At[8192];
    __shared__ __align__(16) char Bl[8192];
    const int t = threadIdx.x;
    const int wid = t >> 6, lane = t & 63;
    const int wr = wid >> 1, wc = wid & 1;
    const int ln = lane & 15, kg = lane >> 4;

    const int f   = blockIdx.x;
    const int xcd = f & 7, jj = f >> 3;
    const int byx = (gridDim.x >> 3) / 2;
    const int by  = xcd * byx + jj / 2;
    const int bx  = jj & 1;

    const char* Ab = (const char*)A  + (size_t)by * 8192;    // tile-major: rows by*128..+128
    const char* Bb = (const char*)Bt + (size_t)bx * 128 * 1024;

    const f32x4 fz = {0.f, 0.f, 0.f, 0.f};
    f32x4 acc[4][4];
#pragma unroll
    for (int i = 0; i < 4; ++i)
#pragma unroll
        for (int j = 0; j < 4; ++j) acc[i][j] = fz;

    for (int s = 0; s < 16; ++s) {
        const size_t kb = (size_t)s * 64;
        const char* As = Ab + (size_t)s * 5242880;           // colTile s: contiguous 8KB
#pragma unroll
        for (int i = 0; i < 2; ++i) {
            int p   = (i * 256 + t) * 16;
            int row = p >> 6;
            int off = (p & 63) ^ ((row & 3) << 4);
            __builtin_amdgcn_global_load_lds((global_cv*)(As + (size_t)row * 64 + off),
                                             (lds_v*)(At + p), 16, 0, 0);
            __builtin_amdgcn_global_load_lds((global_cv*)(Bb + (size_t)row * 1024 + kb + off),
                                             (lds_v*)(Bl + p), 16, 0, 0);
        }
        __syncthreads();
#pragma unroll
        for (int kk = 0; kk < 2; ++kk) {
            i64_t av[4], bv[4];
#pragma unroll
            for (int mt = 0; mt < 4; ++mt) {
                int row = wr * 64 + mt * 16 + ln;
                av[mt] = *(const i64_t*)(At + row * 64 + ((kk * 32 + kg * 8) ^ ((row & 3) << 4)));
            }
#pragma unroll
            for (int nt = 0; nt < 4; ++nt) {
                int row = wc * 64 + nt * 16 + ln;
                bv[nt] = *(const i64_t*)(Bl + row * 64 + ((kk * 32 + kg * 8) ^ ((row & 3) << 4)));
            }
#pragma unroll
            for (int mt = 0; mt < 4; ++mt)
#pragma unroll
                for (int nt = 0; nt < 4; ++nt)
                    acc[mt][nt] = __builtin_amdgcn_mfma_f32_16x16x32_fp8_fp8(bv[nt], av[mt], acc[mt][nt], 0, 0, 0);
        }
        __syncthreads();
    }

#pragma unroll
    for (int mt = 0; mt < 4; ++mt) {
        const int row = by * 128 + wr * 64 + mt * 16 + ln;
#pragma unroll
        for (int nt = 0; nt < 4; ++nt) {
            const int colb = bx * 128 + wc * 64 + nt * 16 + kg * 4;
            const f32x4 a = acc[mt][nt];
            const float4 b4 = *(const float4*)(bias + colb);
            const float4 l4 = *(const float4*)(ls + colb);
            size_t idx = (size_t)row * 256 + colb;
            float4 cur = *(const float4*)(out + idx);
            cur.x += l4.x * (a[0] * 0.00390625f + b4.x);
            cur.y += l4.y * (a[1] * 0.00390625f + b4.y);
            cur.z += l4.z * (a[2] * 0.00390625f + b4.z);
            cur.w += l4.w * (a[3] * 0.00390625f + b4.w);
            *(float4*)(out + idx) = cur;
        }
    }
}

// ---------------- fused per-window attention: per-mt pipeline (r18, unchanged) ----------------
__global__ __launch_bounds__(256) void attn_k(const bf16_t* __restrict__ qkvt,
                                              bf16_t* __restrict__ out)
{
    __shared__ bf16_t Plds[4 * 2 * 1408];   // per wave: 2 x [16][88]
    const int t = threadIdx.x, wid = t >> 6, lane = t & 63;
    const int ln = lane & 15, kg = lane >> 4;
    bf16_t* P0 = &Plds[wid * 2816];
    bf16_t* P1 = P0 + 1408;
    const int b = blockIdx.x;
    const int w = b >> 1;
    const int h = (b & 1) * 4 + wid;
    const float SCALE = 0.17677669529663689f;

    const bf16_t* Qb = qkvt + (size_t)w * 61440 + (size_t)h * 7680;
    const bf16_t* Kb = Qb + 2560;
    const bf16_t* Vb = Qb + 5120;

    bf16x8 kb[5];
#pragma unroll
    for (int nt = 0; nt < 5; ++nt)
        kb[nt] = *(const bf16x8*)(Kb + (nt * 16 + ln) * 32 + kg * 8);

#pragma unroll
    for (int mt = 0; mt < 5; ++mt) {
        bf16x8 qa = *(const bf16x8*)(Qb + (mt * 16 + ln) * 32 + kg * 8);
        f32x4 S[5];
#pragma unroll
        for (int nt = 0; nt < 5; ++nt) {
            f32x4 z = {0.f, 0.f, 0.f, 0.f};
            S[nt] = __builtin_amdgcn_mfma_f32_16x16x32_bf16(qa, kb[nt], z, 0, 0, 0);
        }
#pragma unroll
        for (int r = 0; r < 4; ++r) {
            float mx = S[0][r];
#pragma unroll
            for (int nt = 1; nt < 5; ++nt) mx = fmaxf(mx, S[nt][r]);
            mx = fmaxf(mx, __shfl_xor(mx, 1, 64));
            mx = fmaxf(mx, __shfl_xor(mx, 2, 64));
            mx = fmaxf(mx, __shfl_xor(mx, 4, 64));
            mx = fmaxf(mx, __shfl_xor(mx, 8, 64));
            float sum = 0.f;
#pragma unroll
            for (int nt = 0; nt < 5; ++nt) {
                float e = __expf((S[nt][r] - mx) * SCALE);
                S[nt][r] = e;
                sum += e;
            }
            sum += __shfl_xor(sum, 1, 64);
            sum += __shfl_xor(sum, 2, 64);
            sum += __shfl_xor(sum, 4, 64);
            sum += __shfl_xor(sum, 8, 64);
            float inv = 1.f / sum;
#pragma unroll
            for (int nt = 0; nt < 5; ++nt) S[nt][r] *= inv;
        }
        bf16_t* Pc = (mt & 1) ? P1 : P0;
#pragma unroll
        for (int nt = 0; nt < 5; ++nt)
#pragma unroll
            for (int r = 0; r < 4; ++r)
                Pc[(kg * 4 + r) * 88 + nt * 16 + ln] = (bf16_t)S[nt][r];
        f32x4 O[2];
        O[0] = (f32x4){0.f, 0.f, 0.f, 0.f};
        O[1] = (f32x4){0.f, 0.f, 0.f, 0.f};
#pragma unroll
        for (int nt2 = 0; nt2 < 2; ++nt2) {
#pragma unroll
            for (int kt = 0; kt < 3; ++kt) {
                const bool dead = (kt == 2) && (kg >= 2);
                int off = kt * 32 + kg * 8;
                if (off >= 80) off = 0;
                bf16x8 bv = *(const bf16x8*)(Vb + (nt2 * 16 + ln) * 80 + off);
                if (dead) {
#pragma unroll
                    for (int j = 0; j < 8; ++j) bv[j] = (bf16_t)0.f;
                }
                int cb = kt * 32 + kg * 8;
                if (cb >= 80) cb = 0;
                bf16x8 av = *(const bf16x8*)(Pc + ln * 88 + cb);
                O[nt2] = __builtin_amdgcn_mfma_f32_16x16x32_bf16(av, bv, O[nt2], 0, 0, 0);
            }
        }
#pragma unroll
        for (int nt2 = 0; nt2 < 2; ++nt2)
#pragma unroll
            for (int r = 0; r < 4; ++r) {
                int n = mt * 16 + kg * 4 + r;
                out[((size_t)w * 80 + n) * 256 + h * 32 + nt2 * 16 + ln] = (bf16_t)O[nt2][r];
            }
    }
}

// ---------------- launch ----------------
extern "C" void kernel_launch(void* const* d_in, const int* in_sizes, int n_in,
                              void* d_out, int out_size, void* d_ws, size_t ws_size,
                              hipStream_t stream)
{
    (void)in_sizes; (void)n_in; (void)out_size; (void)ws_size;
    const float* x     = (const float*)d_in[0];
    const float* n1g   = (const float*)d_in[1];
    const float* n1b   = (const float*)d_in[2];
    const float* qkvw  = (const float*)d_in[3];
    const float* qkvb  = (const float*)d_in[4];
    const float* projw = (const float*)d_in[5];
    const float* projb = (const float*)d_in[6];
    const float* ls1   = (const float*)d_in[7];
    const float* n2g   = (const float*)d_in[8];
    const float* n2b   = (const float*)d_in[9];
    const float* fc1w  = (const float*)d_in[10];
    const float* fc1b  = (const float*)d_in[11];
    const float* fc2w  = (const float*)d_in[12];
    const float* fc2b  = (const float*)d_in[13];
    const float* ls2   = (const float*)d_in[14];
    float* out = (float*)d_out;

    // ws (bytes): [0,42MB) actA: ln1p -> attno -> ln2 (sequential reuse)
    //             [42,210MB) big: qkvt 126MB -> h1t fp8 80MB (sequential reuse)
    //             [210MB,..) weights: bf16 ~1MB + fp8 fc2w 256KB
    char* ws = (char*)d_ws;
    bf16_t* actA   = (bf16_t*)(ws);
    bf16_t* qkvt   = (bf16_t*)(ws + 41943040ull);
    unsigned char* h1t = (unsigned char*)(ws + 41943040ull);
    bf16_t* wbuf   = (bf16_t*)(ws + 209715200ull);
    bf16_t* qkvwt  = wbuf;                          // [768][256]
    bf16_t* projwt = qkvwt + 768 * 256;             // [256][256]
    bf16_t* fc1wt  = projwt + 256 * 256;            // [1024][256]
    unsigned char* fc2w8 = (unsigned char*)(fc1wt + 1024 * 256);   // fp8 [256][1024]

    wconvt_k<<<dim3(12, 4), 256, 0, stream>>>(qkvw,  qkvwt, 768, 256);
    wconvt_k<<<dim3(4, 4),  256, 0, stream>>>(projw, projwt, 256, 256);
    wconvt_k<<<dim3(16, 4), 256, 0, stream>>>(fc1w,  fc1wt, 1024, 256);
    wconv8_k<<<256, 256, 0, stream>>>(fc2w, fc2w8);

    ln_k<1><<<20480, 256, 0, stream>>>(x, n1g, n1b, actA);
    gq_k<<<7680, 256, 0, stream>>>(actA, qkvwt, qkvb, qkvt, 768, 256);    // 640 x 12
    attn_k<<<2048, 256, 0, stream>>>(qkvt, actA);
    gp_k<<<2560, 256, 0, stream>>>(actA, projwt, projb, x, ls1, out, 256, 256);   // 640 x 4
    ln_k<0><<<20480, 256, 0, stream>>>(out, n2g, n2b, actA);
    g1_k<<<10240, 256, 0, stream>>>(actA, fc1wt, fc1b, h1t, 1024, 256);   // 640 x 16
    g2f8_k<<<1280, 256, 0, stream>>>(h1t, fc2w8, fc2b, ls2, out);         // 640 x 2
}